// Round 3
// baseline (1470.047 us; speedup 1.0000x reference)
//
#include <hip/hip_runtime.h>
#include <stdint.h>

#define C_IN 512
#define HW 4096
#define NPIX 65536
#define KPAD 544
#define KIN 537
#define HID 512

typedef __attribute__((ext_vector_type(8))) short bf16x8;
typedef __attribute__((ext_vector_type(4))) float f32x4;

__device__ __forceinline__ unsigned short f2bf(float f) {
  union { float f; uint32_t u; } v; v.f = f;
  uint32_t u = v.u;
  return (unsigned short)((u + 0x7fffu + ((u >> 16) & 1u)) >> 16);
}
__device__ __forceinline__ float bf2f(unsigned short h) {
  union { uint32_t u; float f; } v; v.u = ((uint32_t)h) << 16;
  return v.f;
}

// ---------- W: fp32 (512x537) -> bf16 (512x544, zero-padded cols) ----------
__global__ void k_wconv(const float* __restrict__ W, unsigned short* __restrict__ Wb) {
  int idx = blockIdx.x * 256 + threadIdx.x;
  if (idx >= HID * KPAD) return;
  int o = idx / KPAD;
  int k = idx - o * KPAD;
  float v = (k < KIN) ? W[o * KIN + k] : 0.f;
  Wb[idx] = f2bf(v);
}

// ---------- correlation, direct-global (no LDS, no barriers) ----------
// grid 1024 = 8 cs-slices x 128 pixel-blocks; 256 thr; thread = vertical px pair
__global__ __launch_bounds__(256, 3) void k_corr2(const float* __restrict__ x,
                                                  unsigned short* __restrict__ featB,
                                                  unsigned short* __restrict__ part) {
  int bid = blockIdx.x;
  int cs = bid >> 7;        // 0..7 channel slice (64 ch)
  int pb = bid & 127;
  int t = threadIdx.x;
  int p = pb * 256 + t;     // pair index 0..32767 (wave-uniform row, lane = col)
  int c = p & 63;
  int rp = p >> 6;
  int b = rp >> 5;
  int r = (rp & 31) * 2;    // top row of pair
  int n0 = b * 4096 + r * 64 + c;

  // 30 clamped element offsets within one channel image (constant per thread)
  uint32_t off[6][5];
#pragma unroll
  for (int dr = 0; dr < 6; ++dr) {
    int rr = r - 2 + dr; rr = rr < 0 ? 0 : (rr > 63 ? 63 : rr);
#pragma unroll
    for (int dj = 0; dj < 5; ++dj) {
      int cc = c - 2 + dj; cc = cc < 0 ? 0 : (cc > 63 ? 63 : cc);
      off[dr][dj] = rr * 64 + cc;
    }
  }

  float acc0[25], acc1[25];
#pragma unroll
  for (int k = 0; k < 25; ++k) { acc0[k] = 0.f; acc1[k] = 0.f; }

  const float* xc = x + ((size_t)b * C_IN + cs * 64) * HW;  // slice base, this image

#pragma unroll 1
  for (int gq = 0; gq < 4; ++gq) {                 // 4 groups of 16 channels
    uint32_t xb0[8], xb1[8];                       // bf16-packed centers (16 ch)
#pragma unroll
    for (int cl = 0; cl < 16; ++cl) {
      const float* xch = xc + (size_t)(gq * 16 + cl) * HW;
      float v[6][5];
#pragma unroll
      for (int dr = 0; dr < 6; ++dr)
#pragma unroll
        for (int dj = 0; dj < 5; ++dj)
          v[dr][dj] = xch[off[dr][dj]];
      float c0 = v[2][2], c1 = v[3][2];
#pragma unroll
      for (int di = 0; di < 5; ++di)
#pragma unroll
        for (int dj = 0; dj < 5; ++dj) {
          acc0[di * 5 + dj] += c0 * v[di][dj];       // px0 window rows = dr 0..4
          acc1[di * 5 + dj] += c1 * v[di + 1][dj];   // px1 window rows = dr 1..5
        }
      uint32_t h0 = f2bf(c0), h1 = f2bf(c1);
      if (cl & 1) { xb0[cl >> 1] |= h0 << 16; xb1[cl >> 1] |= h1 << 16; }
      else        { xb0[cl >> 1] = h0;        xb1[cl >> 1] = h1; }
    }
    // flush 16 ch (32 B) per pixel; line-aligned base (1088*n % 64 == 0)
    int chb = cs * 64 + gq * 16;
    {
      uint4 u0a = make_uint4(xb0[0], xb0[1], xb0[2], xb0[3]);
      uint4 u0b = make_uint4(xb0[4], xb0[5], xb0[6], xb0[7]);
      uint4 u1a = make_uint4(xb1[0], xb1[1], xb1[2], xb1[3]);
      uint4 u1b = make_uint4(xb1[4], xb1[5], xb1[6], xb1[7]);
      *(uint4*)(featB + (size_t)n0 * KPAD + chb) = u0a;
      *(uint4*)(featB + (size_t)n0 * KPAD + chb + 8) = u0b;
      *(uint4*)(featB + (size_t)(n0 + 64) * KPAD + chb) = u1a;
      *(uint4*)(featB + (size_t)(n0 + 64) * KPAD + chb + 8) = u1b;
    }
  }

  // zero out-of-image terms (exact: reference pads with 0), store partials
#pragma unroll
  for (int di = 0; di < 5; ++di) {
    bool rv0 = (unsigned)(r - 2 + di) < 64u;
    bool rv1 = (unsigned)(r - 1 + di) < 64u;
#pragma unroll
    for (int dj = 0; dj < 5; ++dj) {
      bool cv = (unsigned)(c - 2 + dj) < 64u;
      int k = di * 5 + dj;
      float a0 = (rv0 && cv) ? acc0[k] : 0.f;
      float a1 = (rv1 && cv) ? acc1[k] : 0.f;
      part[((size_t)cs * 25 + k) * NPIX + n0] = f2bf(a0);
      part[((size_t)cs * 25 + k) * NPIX + n0 + 64] = f2bf(a1);
    }
  }
}

// ---------- reduce partials, L2-normalize, emit featB[n][512..543] ----------
__global__ void k_norm(const unsigned short* __restrict__ part,
                       unsigned short* __restrict__ featB) {
  int n = blockIdx.x * 256 + threadIdx.x;
  float g[25];
  float ss = 0.f;
#pragma unroll
  for (int k = 0; k < 25; ++k) {
    float s = 0.f;
#pragma unroll
    for (int cs = 0; cs < 8; ++cs)
      s += bf2f(part[((size_t)cs * 25 + k) * NPIX + n]);
    g[k] = s;
    ss += s * s;
  }
  float inv = 1.0f / sqrtf(ss + 1e-6f);
  unsigned short buf[32];
#pragma unroll
  for (int k = 0; k < 25; ++k) buf[k] = f2bf(g[k] * inv);
#pragma unroll
  for (int k = 25; k < 32; ++k) buf[k] = 0;
#pragma unroll
  for (int j = 0; j < 4; ++j)
    *(bf16x8*)(featB + (size_t)n * KPAD + 512 + j * 8) = *(bf16x8*)&buf[j * 8];
}

// ---------- GEMM: out(512 x 65536) = Wb(512 x 544) * featB(65536 x 544)^T ----------
typedef __attribute__((address_space(3))) unsigned int as3_uint;
typedef const __attribute__((address_space(1))) unsigned int as1_uint;

__device__ __forceinline__ void glds16(const void* g, void* l) {
  __builtin_amdgcn_global_load_lds((as1_uint*)g, (as3_uint*)l, 16, 0, 0);
}

__global__ __launch_bounds__(256) void k_gemm(const unsigned short* __restrict__ Wb,
                                              const unsigned short* __restrict__ featB,
                                              const float* __restrict__ bias,
                                              float* __restrict__ out) {
  __shared__ __attribute__((aligned(16))) unsigned short As[2][4096]; // [128 m][32 k], swz
  __shared__ __attribute__((aligned(16))) unsigned short Bs[2][4096]; // [128 n][32 k], swz
  int g = blockIdx.x;
  int bid = (g & 7) * 256 + (g >> 3);
  int mt = bid & 3;
  int nt = bid >> 2;
  int m0 = mt * 128;
  int n0 = nt * 128;
  int tid = threadIdx.x;
  int wave = tid >> 6;
  int lane = tid & 63;
  int wm = wave >> 1;
  int wn = wave & 1;
  int kg = lane >> 4;

  uint32_t aOff[4], bOff[4];
#pragma unroll
  for (int r = 0; r < 4; ++r) {
    int rr = wm * 64 + r * 16 + (lane & 15);
    aOff[r] = rr * 64 + ((kg ^ ((rr >> 1) & 3)) << 4);
  }
#pragma unroll
  for (int cb = 0; cb < 4; ++cb) {
    int rr = wn * 64 + cb * 16 + (lane & 15);
    bOff[cb] = rr * 64 + ((kg ^ ((rr >> 1) & 3)) << 4);
  }

  f32x4 acc[4][4];
#pragma unroll
  for (int r = 0; r < 4; ++r)
#pragma unroll
    for (int cb = 0; cb < 4; ++cb)
      acc[r][cb] = (f32x4){0.f, 0.f, 0.f, 0.f};

  auto STAGE = [&](int buf, int k0) {
#pragma unroll
    for (int q = 0; q < 2; ++q) {
      int ci = wave * 2 + q;
      int i = ci * 64 + lane;
      int rr = i >> 2;
      int slot = i & 3;
      int k8 = slot ^ ((rr >> 1) & 3);
      glds16(Wb + (size_t)(m0 + rr) * KPAD + k0 + k8 * 8, (char*)&As[buf][0] + ci * 1024);
      glds16(featB + (size_t)(n0 + rr) * KPAD + k0 + k8 * 8, (char*)&Bs[buf][0] + ci * 1024);
    }
  };

  STAGE(0, 0);
  __syncthreads();
  int cur = 0;
#pragma unroll 1
  for (int t = 0; t < 17; ++t) {
    if (t < 16) STAGE(cur ^ 1, (t + 1) * 32);
    const char* Ab = (const char*)&As[cur][0];
    const char* Bb = (const char*)&Bs[cur][0];
    bf16x8 af[4], bf[4];
#pragma unroll
    for (int r = 0; r < 4; ++r)
      af[r] = *(const bf16x8*)(Ab + aOff[r]);
#pragma unroll
    for (int cb = 0; cb < 4; ++cb)
      bf[cb] = *(const bf16x8*)(Bb + bOff[cb]);
#pragma unroll
    for (int cb = 0; cb < 4; ++cb)
#pragma unroll
      for (int r = 0; r < 4; ++r)
        acc[r][cb] = __builtin_amdgcn_mfma_f32_16x16x32_bf16(af[r], bf[cb], acc[r][cb], 0, 0, 0);
    __syncthreads();
    cur ^= 1;
  }

  int bb = n0 >> 12;
  int hwb = n0 & 4095;
  float* outb = out + (size_t)bb * (HID * HW) + hwb;
#pragma unroll
  for (int r = 0; r < 4; ++r) {
    int row0 = m0 + wm * 64 + r * 16 + (lane >> 4) * 4;
    float bv[4];
#pragma unroll
    for (int j = 0; j < 4; ++j) bv[j] = bias[row0 + j];
#pragma unroll
    for (int cb = 0; cb < 4; ++cb) {
      int col = wn * 64 + cb * 16 + (lane & 15);
#pragma unroll
      for (int j = 0; j < 4; ++j) {
        float v2 = acc[r][cb][j] + bv[j];
        v2 = fmaxf(v2, 0.f);
        outb[(size_t)(row0 + j) * HW + col] = v2;
      }
    }
  }
}

extern "C" void kernel_launch(void* const* d_in, const int* in_sizes, int n_in,
                              void* d_out, int out_size, void* d_ws, size_t ws_size,
                              hipStream_t stream) {
  const float* x = (const float*)d_in[0];
  const float* W = (const float*)d_in[1];
  const float* bias = (const float*)d_in[2];
  float* out = (float*)d_out;
  char* ws = (char*)d_ws;
  // ws: featB 65536x544 bf16 = 71,303,168 B; Wb 512x544 bf16 = 557,056 B;
  //     part 8x25x65536 bf16 = 26,214,400 B  (total ~98.07 MB, same as round 2)
  unsigned short* featB = (unsigned short*)ws;
  unsigned short* Wb = (unsigned short*)(ws + 71303168);
  unsigned short* part = (unsigned short*)(ws + 71860224);

  k_wconv<<<1088, 256, 0, stream>>>(W, Wb);
  k_corr2<<<1024, 256, 0, stream>>>(x, featB, part);
  k_norm<<<256, 256, 0, stream>>>(part, featB);
  k_gemm<<<2048, 256, 0, stream>>>(Wb, featB, bias, out);
}

// Round 4
// 740.437 us; speedup vs baseline: 1.9854x; 1.9854x over previous
//
#include <hip/hip_runtime.h>
#include <stdint.h>

#define C_IN 512
#define HW 4096
#define NPIX 65536
#define KPAD 544
#define KIN 537
#define HID 512

typedef __attribute__((ext_vector_type(8))) short bf16x8;
typedef __attribute__((ext_vector_type(4))) float f32x4;

__device__ __forceinline__ unsigned short f2bf(float f) {
  union { float f; uint32_t u; } v; v.f = f;
  uint32_t u = v.u;
  return (unsigned short)((u + 0x7fffu + ((u >> 16) & 1u)) >> 16);
}
__device__ __forceinline__ float bf2f(unsigned short h) {
  union { uint32_t u; float f; } v; v.u = ((uint32_t)h) << 16;
  return v.f;
}
__device__ __forceinline__ int clamp63(int v) { return v < 0 ? 0 : (v > 63 ? 63 : v); }

// ---------- W: fp32 (512x537) -> bf16 (512x544, zero-padded cols) ----------
__global__ void k_wconv(const float* __restrict__ W, unsigned short* __restrict__ Wb) {
  int idx = blockIdx.x * 256 + threadIdx.x;
  if (idx >= HID * KPAD) return;
  int o = idx / KPAD;
  int k = idx - o * KPAD;
  float v = (k < KIN) ? W[o * KIN + k] : 0.f;
  Wb[idx] = f2bf(v);
}

// ---------- correlation: 1 px/thread, 25 accs, LDS ch-pair staging ----------
// grid 512 = 16 img x 16 rowgroups x 2 cs; block 256 = 4 px rows x 64 cols
__global__ __launch_bounds__(256) void k_corr3(const float* __restrict__ x,
                                               unsigned short* __restrict__ featB,
                                               unsigned short* __restrict__ part) {
  int bid = blockIdx.x;
  int cs = bid & 1;
  int rg = (bid >> 1) & 15;
  int b  = bid >> 5;
  int t = threadIdx.x;
  int tr = t >> 6;            // wave id = px row in tile
  int c  = t & 63;            // lane = image column
  int r  = rg * 4 + tr;
  int n  = b * 4096 + r * 64 + c;

  __shared__ float2 sm[512];  // [8 rows][64 cols], row 0 = image row rg*4-2 (clamped)

  const float* xb = x + ((size_t)b * C_IN + cs * 256) * HW;

  // staging: thread owns positions t and t+256 of the 512-slot tile
  int p0 = t, p1 = t + 256;
  int go0 = clamp63(rg * 4 - 2 + (p0 >> 6)) * 64 + (p0 & 63);
  int go1 = clamp63(rg * 4 - 2 + (p1 >> 6)) * 64 + (p1 & 63);

  // 5 window column byte-addresses (clamped); row offset via imm di*512
  uint32_t areg[5];
#pragma unroll
  for (int dj = 0; dj < 5; ++dj)
    areg[dj] = (uint32_t)(tr * 512 + clamp63(c - 2 + dj) * 8);

  float acc[25];
#pragma unroll
  for (int k = 0; k < 25; ++k) acc[k] = 0.f;

  const char* smb = (const char*)sm;

  float s00 = xb[go0], s01 = xb[go1];
  float s10 = xb[HW + go0], s11 = xb[HW + go1];

#pragma unroll 1
  for (int g = 0; g < 8; ++g) {          // 8 groups x 16 ch-pairs = 256 ch
    uint32_t pack[16];
#pragma unroll
    for (int ii = 0; ii < 16; ++ii) {
      int i = g * 16 + ii;
      __syncthreads();                   // prior compute done -> safe to overwrite
      sm[p0] = make_float2(s00, s10);
      sm[p1] = make_float2(s01, s11);
      if (i < 127) {                     // prefetch next pair under compute
        const float* xn = xb + (size_t)(2 * i + 2) * HW;
        s00 = xn[go0]; s01 = xn[go1];
        s10 = xn[HW + go0]; s11 = xn[HW + go1];
      }
      __syncthreads();                   // tile ready
      float2 xc = *(const float2*)(smb + areg[2] + 2 * 512);
#pragma unroll
      for (int di = 0; di < 5; ++di)
#pragma unroll
        for (int dj = 0; dj < 5; ++dj) {
          float2 v = *(const float2*)(smb + areg[dj] + di * 512);
          int k = di * 5 + dj;
          acc[k] = fmaf(xc.x, v.x, acc[k]);
          acc[k] = fmaf(xc.y, v.y, acc[k]);
        }
      pack[ii] = (uint32_t)f2bf(xc.x) | ((uint32_t)f2bf(xc.y) << 16);
    }
    // flush 32 channels = one full 64B line per pixel (no write amplification)
    unsigned short* fb = featB + (size_t)n * KPAD + cs * 256 + g * 32;
#pragma unroll
    for (int j = 0; j < 4; ++j)
      *(uint4*)(fb + j * 8) = *(uint4*)&pack[j * 4];
  }

  // zero out-of-image terms exactly (reference zero-pads), store partials
#pragma unroll
  for (int di = 0; di < 5; ++di) {
    bool rv = (unsigned)(r - 2 + di) < 64u;
#pragma unroll
    for (int dj = 0; dj < 5; ++dj) {
      bool cv = (unsigned)(c - 2 + dj) < 64u;
      int k = di * 5 + dj;
      part[((size_t)cs * 25 + k) * NPIX + n] = f2bf((rv && cv) ? acc[k] : 0.f);
    }
  }
}

// ---------- reduce 2 partials, L2-normalize, emit featB[n][512..543] ----------
__global__ void k_norm(const unsigned short* __restrict__ part,
                       unsigned short* __restrict__ featB) {
  int n = blockIdx.x * 256 + threadIdx.x;
  float g[25];
  float ss = 0.f;
#pragma unroll
  for (int k = 0; k < 25; ++k) {
    float s = bf2f(part[(size_t)k * NPIX + n]) + bf2f(part[(size_t)(25 + k) * NPIX + n]);
    g[k] = s;
    ss += s * s;
  }
  float inv = 1.0f / sqrtf(ss + 1e-6f);
  unsigned short buf[32];
#pragma unroll
  for (int k = 0; k < 25; ++k) buf[k] = f2bf(g[k] * inv);
#pragma unroll
  for (int k = 25; k < 32; ++k) buf[k] = 0;
#pragma unroll
  for (int j = 0; j < 4; ++j)
    *(bf16x8*)(featB + (size_t)n * KPAD + 512 + j * 8) = *(bf16x8*)&buf[j * 8];
}

// ---------- GEMM: out(512 x 65536) = Wb(512 x 544) * featB(65536 x 544)^T ----------
typedef __attribute__((address_space(3))) unsigned int as3_uint;
typedef const __attribute__((address_space(1))) unsigned int as1_uint;

__device__ __forceinline__ void glds16(const void* g, void* l) {
  __builtin_amdgcn_global_load_lds((as1_uint*)g, (as3_uint*)l, 16, 0, 0);
}

__global__ __launch_bounds__(256) void k_gemm(const unsigned short* __restrict__ Wb,
                                              const unsigned short* __restrict__ featB,
                                              const float* __restrict__ bias,
                                              float* __restrict__ out) {
  __shared__ __attribute__((aligned(16))) unsigned short As[2][4096]; // [128 m][32 k], swz
  __shared__ __attribute__((aligned(16))) unsigned short Bs[2][4096]; // [128 n][32 k], swz
  int g = blockIdx.x;
  int bid = (g & 7) * 256 + (g >> 3);
  int mt = bid & 3;
  int nt = bid >> 2;
  int m0 = mt * 128;
  int n0 = nt * 128;
  int tid = threadIdx.x;
  int wave = tid >> 6;
  int lane = tid & 63;
  int wm = wave >> 1;
  int wn = wave & 1;
  int kg = lane >> 4;

  uint32_t aOff[4], bOff[4];
#pragma unroll
  for (int r = 0; r < 4; ++r) {
    int rr = wm * 64 + r * 16 + (lane & 15);
    aOff[r] = rr * 64 + ((kg ^ ((rr >> 1) & 3)) << 4);
  }
#pragma unroll
  for (int cb = 0; cb < 4; ++cb) {
    int rr = wn * 64 + cb * 16 + (lane & 15);
    bOff[cb] = rr * 64 + ((kg ^ ((rr >> 1) & 3)) << 4);
  }

  f32x4 acc[4][4];
#pragma unroll
  for (int r = 0; r < 4; ++r)
#pragma unroll
    for (int cb = 0; cb < 4; ++cb)
      acc[r][cb] = (f32x4){0.f, 0.f, 0.f, 0.f};

  auto STAGE = [&](int buf, int k0) {
#pragma unroll
    for (int q = 0; q < 2; ++q) {
      int ci = wave * 2 + q;
      int i = ci * 64 + lane;
      int rr = i >> 2;
      int slot = i & 3;
      int k8 = slot ^ ((rr >> 1) & 3);
      glds16(Wb + (size_t)(m0 + rr) * KPAD + k0 + k8 * 8, (char*)&As[buf][0] + ci * 1024);
      glds16(featB + (size_t)(n0 + rr) * KPAD + k0 + k8 * 8, (char*)&Bs[buf][0] + ci * 1024);
    }
  };

  STAGE(0, 0);
  __syncthreads();
  int cur = 0;
#pragma unroll 1
  for (int t = 0; t < 17; ++t) {
    if (t < 16) STAGE(cur ^ 1, (t + 1) * 32);
    const char* Ab = (const char*)&As[cur][0];
    const char* Bb = (const char*)&Bs[cur][0];
    bf16x8 af[4], bf[4];
#pragma unroll
    for (int r = 0; r < 4; ++r)
      af[r] = *(const bf16x8*)(Ab + aOff[r]);
#pragma unroll
    for (int cb = 0; cb < 4; ++cb)
      bf[cb] = *(const bf16x8*)(Bb + bOff[cb]);
#pragma unroll
    for (int cb = 0; cb < 4; ++cb)
#pragma unroll
      for (int r = 0; r < 4; ++r)
        acc[r][cb] = __builtin_amdgcn_mfma_f32_16x16x32_bf16(af[r], bf[cb], acc[r][cb], 0, 0, 0);
    __syncthreads();
    cur ^= 1;
  }

  int bb = n0 >> 12;
  int hwb = n0 & 4095;
  float* outb = out + (size_t)bb * (HID * HW) + hwb;
#pragma unroll
  for (int r = 0; r < 4; ++r) {
    int row0 = m0 + wm * 64 + r * 16 + (lane >> 4) * 4;
    float bv[4];
#pragma unroll
    for (int j = 0; j < 4; ++j) bv[j] = bias[row0 + j];
#pragma unroll
    for (int cb = 0; cb < 4; ++cb) {
      int col = wn * 64 + cb * 16 + (lane & 15);
#pragma unroll
      for (int j = 0; j < 4; ++j) {
        float v2 = acc[r][cb][j] + bv[j];
        v2 = fmaxf(v2, 0.f);
        outb[(size_t)(row0 + j) * HW + col] = v2;
      }
    }
  }
}

extern "C" void kernel_launch(void* const* d_in, const int* in_sizes, int n_in,
                              void* d_out, int out_size, void* d_ws, size_t ws_size,
                              hipStream_t stream) {
  const float* x = (const float*)d_in[0];
  const float* W = (const float*)d_in[1];
  const float* bias = (const float*)d_in[2];
  float* out = (float*)d_out;
  char* ws = (char*)d_ws;
  // ws: featB 65536x544 bf16 = 71,303,168 B; Wb 512x544 bf16 = 557,056 B;
  //     part 2x25x65536 bf16 = 6,553,600 B  (total ~78.4 MB)
  unsigned short* featB = (unsigned short*)ws;
  unsigned short* Wb = (unsigned short*)(ws + 71303168);
  unsigned short* part = (unsigned short*)(ws + 71860224);

  k_wconv<<<1088, 256, 0, stream>>>(W, Wb);
  k_corr3<<<512, 256, 0, stream>>>(x, featB, part);
  k_norm<<<256, 256, 0, stream>>>(part, featB);
  k_gemm<<<2048, 256, 0, stream>>>(Wb, featB, bias, out);
}

// Round 5
// 204.828 us; speedup vs baseline: 7.1770x; 3.6149x over previous
//
#include <hip/hip_runtime.h>
#include <stdint.h>

#define C_IN 512
#define HW 4096
#define NPIX 65536
#define KPAD 544
#define KIN 537
#define HID 512

typedef __attribute__((ext_vector_type(8))) short bf16x8;
typedef __attribute__((ext_vector_type(4))) float f32x4;

__device__ __forceinline__ unsigned short f2bf(float f) {
  union { float f; uint32_t u; } v; v.f = f;
  uint32_t u = v.u;
  return (unsigned short)((u + 0x7fffu + ((u >> 16) & 1u)) >> 16);
}
__device__ __forceinline__ float bf2f(unsigned short h) {
  union { uint32_t u; float f; } v; v.u = ((uint32_t)h) << 16;
  return v.f;
}

// ---------- W: fp32 (512x537) -> bf16 (512x544, zero-padded cols) ----------
__global__ void k_wconv(const float* __restrict__ W, unsigned short* __restrict__ Wb) {
  int idx = blockIdx.x * 256 + threadIdx.x;
  if (idx >= HID * KPAD) return;
  int o = idx / KPAD;
  int k = idx - o * KPAD;
  float v = (k < KIN) ? W[o * KIN + k] : 0.f;
  Wb[idx] = f2bf(v);
}

// ---------- MFMA correlation + fused x->featB transpose ----------
// grid 2048 = 16 img x 16 rowgroups x 8 cs (XCD-swizzled: 2 images per XCD)
// block 256 = 4 waves, wave w = image row r0+w. LDS tile [8 sr][68 sc][64 ch] bf16.
// elem(sr,sc,kg): kg(8ch)-unit XOR-swizzled by ((sc>>1)&3) -> conflict-free b128 r/w.
__device__ __forceinline__ int xelem(int sr, int sc, int kg) {
  return (sr * 68 + sc) * 64 + ((kg ^ ((sc >> 1) & 3)) * 8);
}

__global__ __launch_bounds__(256) void k_corr(const float* __restrict__ x,
                                              unsigned short* __restrict__ featB,
                                              unsigned short* __restrict__ part) {
  __shared__ unsigned short xt[8 * 68 * 64];  // 69,632 B -> 2 blocks/CU
  int g = blockIdx.x;
  int bid = (g & 7) * 256 + (g >> 3);   // XCD k owns bid in [k*256,(k+1)*256)
  int cs = bid & 7;
  int rg = (bid >> 3) & 15;
  int b  = bid >> 7;
  int t = threadIdx.x;
  int lane = t & 63;
  int w = t >> 6;
  int r0 = rg * 4;

  const float* xb = x + ((size_t)b * C_IN + cs * 64) * HW;

  // ---- stage: (sr = w, w+4) x (col = lane); image rows r0-2+sr, zero-padded
#pragma unroll
  for (int s = 0; s < 2; ++s) {
    int sr = w + s * 4;
    int ir = r0 - 2 + sr;
    int sc = lane + 2;
    if ((unsigned)ir < 64u) {
      const float* src = xb + ir * 64 + lane;
#pragma unroll 2
      for (int kg = 0; kg < 8; ++kg) {
        unsigned short pk[8];
#pragma unroll
        for (int j = 0; j < 8; ++j) pk[j] = f2bf(src[(kg * 8 + j) * HW]);
        *(bf16x8*)&xt[xelem(sr, sc, kg)] = *(bf16x8*)pk;
      }
    } else {
      bf16x8 z = (bf16x8){0, 0, 0, 0, 0, 0, 0, 0};
#pragma unroll
      for (int kg = 0; kg < 8; ++kg)
        *(bf16x8*)&xt[xelem(sr, sc, kg)] = z;
    }
  }
  // ---- zero the 4 halo cols (sc = 0,1,66,67): 256 threads x 1 write
  {
    int kg = t & 7, sr = (t >> 3) & 7, qq = t >> 6;
    int sc = (qq < 2) ? qq : (qq + 64);   // 0,1,66,67
    bf16x8 z = (bf16x8){0, 0, 0, 0, 0, 0, 0, 0};
    *(bf16x8*)&xt[xelem(sr, sc, kg)] = z;
  }
  __syncthreads();

  // ---- fused featB transpose: px (r0+w, lane), 64 ch from LDS, 128B/px stores
  {
    int n = b * 4096 + (r0 + w) * 64 + lane;
    unsigned short* fb = featB + (size_t)n * KPAD + cs * 64;
#pragma unroll
    for (int kg = 0; kg < 8; ++kg)
      *(bf16x8*)(fb + kg * 8) = *(const bf16x8*)&xt[xelem(w + 2, lane + 2, kg)];
  }

  // ---- MFMA: wave computes 25 (di,dj) diag-tiles for its 64 px row
  int i15 = lane & 15;
  int tq = lane >> 4;
  int q = i15 - tq * 4;                 // diag reg index; valid in [0,4)
  bool valid = (q >= 0) && (q < 4);

  bf16x8 afr[4][2];                     // A-frags: centers, reused for all 25
#pragma unroll
  for (int gg = 0; gg < 4; ++gg)
#pragma unroll
    for (int ks = 0; ks < 2; ++ks)
      afr[gg][ks] = *(const bf16x8*)&xt[xelem(w + 2, gg * 16 + 2 + i15, ks * 4 + tq)];

  int nb = b * 4096 + (r0 + w) * 64;
#pragma unroll 1
  for (int di = 0; di < 5; ++di) {
    int sr = w + di;
    unsigned short* pbase = part + ((size_t)(cs * 25 + di * 5)) * NPIX + nb;
#pragma unroll
    for (int dj = 0; dj < 5; ++dj) {
      f32x4 acc[4];
#pragma unroll
      for (int gg = 0; gg < 4; ++gg) acc[gg] = (f32x4){0.f, 0.f, 0.f, 0.f};
#pragma unroll
      for (int gg = 0; gg < 4; ++gg)
#pragma unroll
        for (int ks = 0; ks < 2; ++ks) {
          bf16x8 bfr = *(const bf16x8*)&xt[xelem(sr, gg * 16 + dj + i15, ks * 4 + tq)];
          acc[gg] = __builtin_amdgcn_mfma_f32_16x16x32_bf16(afr[gg][ks], bfr, acc[gg], 0, 0, 0);
        }
      unsigned short* pp = pbase + (size_t)dj * NPIX;
#pragma unroll
      for (int gg = 0; gg < 4; ++gg) {
        float val = (q == 0) ? acc[gg][0]
                  : (q == 1) ? acc[gg][1]
                  : (q == 2) ? acc[gg][2] : acc[gg][3];
        if (valid) pp[gg * 16 + i15] = f2bf(val);
      }
    }
  }
}

// ---------- reduce 8 partials, L2-normalize, emit featB[n][512..543] ----------
__global__ void k_norm(const unsigned short* __restrict__ part,
                       unsigned short* __restrict__ featB) {
  int n = blockIdx.x * 256 + threadIdx.x;
  float g[25];
  float ss = 0.f;
#pragma unroll
  for (int k = 0; k < 25; ++k) {
    float s = 0.f;
#pragma unroll
    for (int cs = 0; cs < 8; ++cs)
      s += bf2f(part[((size_t)cs * 25 + k) * NPIX + n]);
    g[k] = s;
    ss += s * s;
  }
  float inv = 1.0f / sqrtf(ss + 1e-6f);
  unsigned short buf[32];
#pragma unroll
  for (int k = 0; k < 25; ++k) buf[k] = f2bf(g[k] * inv);
#pragma unroll
  for (int k = 25; k < 32; ++k) buf[k] = 0;
#pragma unroll
  for (int j = 0; j < 4; ++j)
    *(bf16x8*)(featB + (size_t)n * KPAD + 512 + j * 8) = *(bf16x8*)&buf[j * 8];
}

// ---------- GEMM: out(512 x 65536) = Wb(512 x 544) * featB(65536 x 544)^T ----------
typedef __attribute__((address_space(3))) unsigned int as3_uint;
typedef const __attribute__((address_space(1))) unsigned int as1_uint;

__device__ __forceinline__ void glds16(const void* g, void* l) {
  __builtin_amdgcn_global_load_lds((as1_uint*)g, (as3_uint*)l, 16, 0, 0);
}

__global__ __launch_bounds__(256) void k_gemm(const unsigned short* __restrict__ Wb,
                                              const unsigned short* __restrict__ featB,
                                              const float* __restrict__ bias,
                                              float* __restrict__ out) {
  __shared__ __attribute__((aligned(16))) unsigned short As[2][4096]; // [128 m][32 k], swz
  __shared__ __attribute__((aligned(16))) unsigned short Bs[2][4096]; // [128 n][32 k], swz
  int g = blockIdx.x;
  int bid = (g & 7) * 256 + (g >> 3);
  int mt = bid & 3;
  int nt = bid >> 2;
  int m0 = mt * 128;
  int n0 = nt * 128;
  int tid = threadIdx.x;
  int wave = tid >> 6;
  int lane = tid & 63;
  int wm = wave >> 1;
  int wn = wave & 1;
  int kg = lane >> 4;

  uint32_t aOff[4], bOff[4];
#pragma unroll
  for (int r = 0; r < 4; ++r) {
    int rr = wm * 64 + r * 16 + (lane & 15);
    aOff[r] = rr * 64 + ((kg ^ ((rr >> 1) & 3)) << 4);
  }
#pragma unroll
  for (int cb = 0; cb < 4; ++cb) {
    int rr = wn * 64 + cb * 16 + (lane & 15);
    bOff[cb] = rr * 64 + ((kg ^ ((rr >> 1) & 3)) << 4);
  }

  f32x4 acc[4][4];
#pragma unroll
  for (int r = 0; r < 4; ++r)
#pragma unroll
    for (int cb = 0; cb < 4; ++cb)
      acc[r][cb] = (f32x4){0.f, 0.f, 0.f, 0.f};

  auto STAGE = [&](int buf, int k0) {
#pragma unroll
    for (int qq = 0; qq < 2; ++qq) {
      int ci = wave * 2 + qq;
      int i = ci * 64 + lane;
      int rr = i >> 2;
      int slot = i & 3;
      int k8 = slot ^ ((rr >> 1) & 3);
      glds16(Wb + (size_t)(m0 + rr) * KPAD + k0 + k8 * 8, (char*)&As[buf][0] + ci * 1024);
      glds16(featB + (size_t)(n0 + rr) * KPAD + k0 + k8 * 8, (char*)&Bs[buf][0] + ci * 1024);
    }
  };

  STAGE(0, 0);
  __syncthreads();
  int cur = 0;
#pragma unroll 1
  for (int t = 0; t < 17; ++t) {
    if (t < 16) STAGE(cur ^ 1, (t + 1) * 32);
    const char* Ab = (const char*)&As[cur][0];
    const char* Bb = (const char*)&Bs[cur][0];
    bf16x8 af[4], bf[4];
#pragma unroll
    for (int r = 0; r < 4; ++r)
      af[r] = *(const bf16x8*)(Ab + aOff[r]);
#pragma unroll
    for (int cb = 0; cb < 4; ++cb)
      bf[cb] = *(const bf16x8*)(Bb + bOff[cb]);
#pragma unroll
    for (int cb = 0; cb < 4; ++cb)
#pragma unroll
      for (int r = 0; r < 4; ++r)
        acc[r][cb] = __builtin_amdgcn_mfma_f32_16x16x32_bf16(af[r], bf[cb], acc[r][cb], 0, 0, 0);
    __syncthreads();
    cur ^= 1;
  }

  int bb = n0 >> 12;
  int hwb = n0 & 4095;
  float* outb = out + (size_t)bb * (HID * HW) + hwb;
#pragma unroll
  for (int r = 0; r < 4; ++r) {
    int row0 = m0 + wm * 64 + r * 16 + (lane >> 4) * 4;
    float bv[4];
#pragma unroll
    for (int j = 0; j < 4; ++j) bv[j] = bias[row0 + j];
#pragma unroll
    for (int cb = 0; cb < 4; ++cb) {
      int col = wn * 64 + cb * 16 + (lane & 15);
#pragma unroll
      for (int j = 0; j < 4; ++j) {
        float v2 = acc[r][cb][j] + bv[j];
        v2 = fmaxf(v2, 0.f);
        outb[(size_t)(row0 + j) * HW + col] = v2;
      }
    }
  }
}

extern "C" void kernel_launch(void* const* d_in, const int* in_sizes, int n_in,
                              void* d_out, int out_size, void* d_ws, size_t ws_size,
                              hipStream_t stream) {
  const float* x = (const float*)d_in[0];
  const float* W = (const float*)d_in[1];
  const float* bias = (const float*)d_in[2];
  float* out = (float*)d_out;
  char* ws = (char*)d_ws;
  // ws: featB 65536x544 bf16 = 71,303,168 B; Wb 512x544 bf16 = 557,056 B;
  //     part 8x25x65536 bf16 = 26,214,400 B  (total ~98.07 MB)
  unsigned short* featB = (unsigned short*)ws;
  unsigned short* Wb = (unsigned short*)(ws + 71303168);
  unsigned short* part = (unsigned short*)(ws + 71860224);

  k_wconv<<<1088, 256, 0, stream>>>(W, Wb);
  k_corr<<<2048, 256, 0, stream>>>(x, featB, part);
  k_norm<<<256, 256, 0, stream>>>(part, featB);
  k_gemm<<<2048, 256, 0, stream>>>(Wb, featB, bias, out);
}

// Round 7
// 202.610 us; speedup vs baseline: 7.2555x; 1.0109x over previous
//
#include <hip/hip_runtime.h>
#include <stdint.h>

#define C_IN 512
#define HW 4096
#define NPIX 65536
#define KPAD 544
#define KIN 537
#define HID 512

typedef __attribute__((ext_vector_type(8))) short bf16x8;
typedef __attribute__((ext_vector_type(4))) float f32x4;

__device__ __forceinline__ unsigned short f2bf(float f) {
  union { float f; uint32_t u; } v; v.f = f;
  uint32_t u = v.u;
  return (unsigned short)((u + 0x7fffu + ((u >> 16) & 1u)) >> 16);
}
__device__ __forceinline__ float bf2f(unsigned short h) {
  union { uint32_t u; float f; } v; v.u = ((uint32_t)h) << 16;
  return v.f;
}

// ---------- W: fp32 (512x537) -> bf16 (512x544, zero-padded cols) ----------
__global__ void k_wconv(const float* __restrict__ W, unsigned short* __restrict__ Wb) {
  int idx = blockIdx.x * 256 + threadIdx.x;
  if (idx >= HID * KPAD) return;
  int o = idx / KPAD;
  int k = idx - o * KPAD;
  float v = (k < KIN) ? W[o * KIN + k] : 0.f;
  Wb[idx] = f2bf(v);
}

// ---------- MFMA correlation + fused x->featB transpose (round-5 geometry) ----------
// grid 2048 = 16 img x 16 rowgroups x 8 cs (XCD-swizzled), block 256 = 4 waves,
// wave w = image row r0+w. LDS tile [8 sr][68 sc][64 ch] bf16, zero-padded halo.
// Swizzle FIX vs round 5: slot = kg ^ (sc&7) spreads b128 frags over all 8 16B
// slots (round 5's (sc>>1)&3 used only 4 -> 2x the inherent wave64-b128 floor).
__device__ __forceinline__ int xelem(int sr, int sc, int kg) {
  return (sr * 68 + sc) * 64 + ((kg ^ (sc & 7)) * 8);
}

__global__ __launch_bounds__(256) void k_corr(const float* __restrict__ x,
                                              unsigned short* __restrict__ featB,
                                              unsigned short* __restrict__ part) {
  __shared__ unsigned short xt[8 * 68 * 64];  // 69,632 B -> 2 blocks/CU
  int g = blockIdx.x;
  int bid = (g & 7) * 256 + (g >> 3);   // bijective XCD swizzle (grid = 8*256)
  int cs = bid & 7;
  int rg = (bid >> 3) & 15;
  int b  = bid >> 7;
  int t = threadIdx.x;
  int lane = t & 63;
  int w = t >> 6;
  int r0 = rg * 4;

  const float* xb = x + ((size_t)b * C_IN + cs * 64) * HW;

  // ---- stage rows (w, w+4), col lane; image rows r0-2+sr, zero-padded
#pragma unroll
  for (int s = 0; s < 2; ++s) {
    int sr = w + s * 4;
    int ir = r0 - 2 + sr;
    int sc = lane + 2;
    if ((unsigned)ir < 64u) {
      const float* src = xb + ir * 64 + lane;
#pragma unroll 2
      for (int kg = 0; kg < 8; ++kg) {
        unsigned short pk[8];
#pragma unroll
        for (int j = 0; j < 8; ++j) pk[j] = f2bf(src[(kg * 8 + j) * HW]);
        *(bf16x8*)&xt[xelem(sr, sc, kg)] = *(bf16x8*)pk;
      }
    } else {
      bf16x8 z = (bf16x8){0, 0, 0, 0, 0, 0, 0, 0};
#pragma unroll
      for (int kg = 0; kg < 8; ++kg)
        *(bf16x8*)&xt[xelem(sr, sc, kg)] = z;
    }
  }
  // ---- zero the 4 halo cols (sc = 0,1,66,67): 256 threads x 1 write
  {
    int kg = t & 7, sr = (t >> 3) & 7, qq = t >> 6;
    int sc = (qq < 2) ? qq : (qq + 64);   // 0,1,66,67
    bf16x8 z = (bf16x8){0, 0, 0, 0, 0, 0, 0, 0};
    *(bf16x8*)&xt[xelem(sr, sc, kg)] = z;
  }
  __syncthreads();

  // ---- fused featB transpose: px (r0+w, lane), 64 ch from LDS, 128B/px stores
  {
    int n = b * 4096 + (r0 + w) * 64 + lane;
    unsigned short* fb = featB + (size_t)n * KPAD + cs * 64;
#pragma unroll
    for (int kg = 0; kg < 8; ++kg)
      *(bf16x8*)(fb + kg * 8) = *(const bf16x8*)&xt[xelem(w + 2, lane + 2, kg)];
  }

  // ---- MFMA: wave computes 25 (di,dj) diag-tiles for its 64 px row
  int i15 = lane & 15;
  int tq = lane >> 4;
  int q = i15 - tq * 4;                 // diag reg index; valid in [0,4)
  bool valid = (q >= 0) && (q < 4);

  bf16x8 afr[4][2];                     // A-frags: centers, reused for all 25
#pragma unroll
  for (int gg = 0; gg < 4; ++gg)
#pragma unroll
    for (int ks = 0; ks < 2; ++ks)
      afr[gg][ks] = *(const bf16x8*)&xt[xelem(w + 2, gg * 16 + 2 + i15, ks * 4 + tq)];

  int nb = b * 4096 + (r0 + w) * 64;
#pragma unroll 1
  for (int di = 0; di < 5; ++di) {
    int sr = w + di;
    unsigned short* pbase = part + ((size_t)(cs * 25 + di * 5)) * NPIX + nb;
#pragma unroll
    for (int dj = 0; dj < 5; ++dj) {
      f32x4 acc[4];
#pragma unroll
      for (int gg = 0; gg < 4; ++gg) acc[gg] = (f32x4){0.f, 0.f, 0.f, 0.f};
#pragma unroll
      for (int gg = 0; gg < 4; ++gg)
#pragma unroll
        for (int ks = 0; ks < 2; ++ks) {
          bf16x8 bfr = *(const bf16x8*)&xt[xelem(sr, gg * 16 + dj + i15, ks * 4 + tq)];
          acc[gg] = __builtin_amdgcn_mfma_f32_16x16x32_bf16(afr[gg][ks], bfr, acc[gg], 0, 0, 0);
        }
      unsigned short* pp = pbase + (size_t)dj * NPIX;
#pragma unroll
      for (int gg = 0; gg < 4; ++gg) {
        float val = (q == 0) ? acc[gg][0]
                  : (q == 1) ? acc[gg][1]
                  : (q == 2) ? acc[gg][2] : acc[gg][3];
        if (valid) pp[gg * 16 + i15] = f2bf(val);
      }
    }
  }
}

// ---------- reduce 8 partials, L2-normalize, emit featB[n][512..543] ----------
__global__ void k_norm(const unsigned short* __restrict__ part,
                       unsigned short* __restrict__ featB) {
  int n = blockIdx.x * 256 + threadIdx.x;
  float g[25];
  float ss = 0.f;
#pragma unroll
  for (int k = 0; k < 25; ++k) {
    float s = 0.f;
#pragma unroll
    for (int cs = 0; cs < 8; ++cs)
      s += bf2f(part[((size_t)cs * 25 + k) * NPIX + n]);
    g[k] = s;
    ss += s * s;
  }
  float inv = 1.0f / sqrtf(ss + 1e-6f);
  unsigned short buf[32];
#pragma unroll
  for (int k = 0; k < 25; ++k) buf[k] = f2bf(g[k] * inv);
#pragma unroll
  for (int k = 25; k < 32; ++k) buf[k] = 0;
#pragma unroll
  for (int j = 0; j < 4; ++j)
    *(bf16x8*)(featB + (size_t)n * KPAD + 512 + j * 8) = *(bf16x8*)&buf[j * 8];
}

// ---------- GEMM: out(512 x 65536) = Wb(512 x 544) * featB(65536 x 544)^T ----------
typedef __attribute__((address_space(3))) unsigned int as3_uint;
typedef const __attribute__((address_space(1))) unsigned int as1_uint;

__device__ __forceinline__ void glds16(const void* g, void* l) {
  __builtin_amdgcn_global_load_lds((as1_uint*)g, (as3_uint*)l, 16, 0, 0);
}

__global__ __launch_bounds__(256) void k_gemm(const unsigned short* __restrict__ Wb,
                                              const unsigned short* __restrict__ featB,
                                              const float* __restrict__ bias,
                                              float* __restrict__ out) {
  __shared__ __attribute__((aligned(16))) unsigned short As[2][4096]; // [128 m][32 k], swz
  __shared__ __attribute__((aligned(16))) unsigned short Bs[2][4096]; // [128 n][32 k], swz
  int g = blockIdx.x;
  int bid = (g & 7) * 256 + (g >> 3);
  int mt = bid & 3;
  int nt = bid >> 2;
  int m0 = mt * 128;
  int n0 = nt * 128;
  int tid = threadIdx.x;
  int wave = tid >> 6;
  int lane = tid & 63;
  int wm = wave >> 1;
  int wn = wave & 1;
  int kg = lane >> 4;

  uint32_t aOff[4], bOff[4];
#pragma unroll
  for (int r = 0; r < 4; ++r) {
    int rr = wm * 64 + r * 16 + (lane & 15);
    aOff[r] = rr * 64 + ((kg ^ ((rr >> 1) & 3)) << 4);
  }
#pragma unroll
  for (int cb = 0; cb < 4; ++cb) {
    int rr = wn * 64 + cb * 16 + (lane & 15);
    bOff[cb] = rr * 64 + ((kg ^ ((rr >> 1) & 3)) << 4);
  }

  f32x4 acc[4][4];
#pragma unroll
  for (int r = 0; r < 4; ++r)
#pragma unroll
    for (int cb = 0; cb < 4; ++cb)
      acc[r][cb] = (f32x4){0.f, 0.f, 0.f, 0.f};

  auto STAGE = [&](int buf, int k0) {
#pragma unroll
    for (int qq = 0; qq < 2; ++qq) {
      int ci = wave * 2 + qq;
      int i = ci * 64 + lane;
      int rr = i >> 2;
      int slot = i & 3;
      int k8 = slot ^ ((rr >> 1) & 3);
      glds16(Wb + (size_t)(m0 + rr) * KPAD + k0 + k8 * 8, (char*)&As[buf][0] + ci * 1024);
      glds16(featB + (size_t)(n0 + rr) * KPAD + k0 + k8 * 8, (char*)&Bs[buf][0] + ci * 1024);
    }
  };

  STAGE(0, 0);
  __syncthreads();
  int cur = 0;
#pragma unroll 1
  for (int t = 0; t < 17; ++t) {
    if (t < 16) STAGE(cur ^ 1, (t + 1) * 32);
    const char* Ab = (const char*)&As[cur][0];
    const char* Bb = (const char*)&Bs[cur][0];
    bf16x8 af[4], bf[4];
#pragma unroll
    for (int r = 0; r < 4; ++r)
      af[r] = *(const bf16x8*)(Ab + aOff[r]);
#pragma unroll
    for (int cb = 0; cb < 4; ++cb)
      bf[cb] = *(const bf16x8*)(Bb + bOff[cb]);
#pragma unroll
    for (int cb = 0; cb < 4; ++cb)
#pragma unroll
      for (int r = 0; r < 4; ++r)
        acc[r][cb] = __builtin_amdgcn_mfma_f32_16x16x32_bf16(af[r], bf[cb], acc[r][cb], 0, 0, 0);
    __syncthreads();
    cur ^= 1;
  }

  int bb = n0 >> 12;
  int hwb = n0 & 4095;
  float* outb = out + (size_t)bb * (HID * HW) + hwb;
#pragma unroll
  for (int r = 0; r < 4; ++r) {
    int row0 = m0 + wm * 64 + r * 16 + (lane >> 4) * 4;
    float bv[4];
#pragma unroll
    for (int j = 0; j < 4; ++j) bv[j] = bias[row0 + j];
#pragma unroll
    for (int cb = 0; cb < 4; ++cb) {
      int col = wn * 64 + cb * 16 + (lane & 15);
#pragma unroll
      for (int j = 0; j < 4; ++j) {
        float v2 = acc[r][cb][j] + bv[j];
        v2 = fmaxf(v2, 0.f);
        outb[(size_t)(row0 + j) * HW + col] = v2;
      }
    }
  }
}

extern "C" void kernel_launch(void* const* d_in, const int* in_sizes, int n_in,
                              void* d_out, int out_size, void* d_ws, size_t ws_size,
                              hipStream_t stream) {
  const float* x = (const float*)d_in[0];
  const float* W = (const float*)d_in[1];
  const float* bias = (const float*)d_in[2];
  float* out = (float*)d_out;
  char* ws = (char*)d_ws;
  // ws: featB 65536x544 bf16 = 71,303,168; Wb 512x544 bf16 = 557,056;
  //     part 8x25x65536 bf16 = 26,214,400  (total ~98.07 MB)
  unsigned short* featB = (unsigned short*)ws;
  unsigned short* Wb = (unsigned short*)(ws + 71303168);
  unsigned short* part = (unsigned short*)(ws + 71860224);

  k_wconv<<<1088, 256, 0, stream>>>(W, Wb);
  k_corr<<<2048, 256, 0, stream>>>(x, featB, part);
  k_norm<<<256, 256, 0, stream>>>(part, featB);
  k_gemm<<<2048, 256, 0, stream>>>(Wb, featB, bias, out);
}

// Round 8
// 177.272 us; speedup vs baseline: 8.2926x; 1.1429x over previous
//
#include <hip/hip_runtime.h>
#include <stdint.h>

#define C_IN 512
#define HW 4096
#define NPIX 65536
#define KPAD 544
#define KIN 537
#define HID 512

typedef __attribute__((ext_vector_type(8))) short bf16x8;
typedef __attribute__((ext_vector_type(4))) float f32x4;

__device__ __forceinline__ unsigned short f2bf(float f) {
  union { float f; uint32_t u; } v; v.f = f;
  uint32_t u = v.u;
  return (unsigned short)((u + 0x7fffu + ((u >> 16) & 1u)) >> 16);
}
__device__ __forceinline__ float bf2f(unsigned short h) {
  union { uint32_t u; float f; } v; v.u = ((uint32_t)h) << 16;
  return v.f;
}

// ---------- W: fp32 (512x537) -> bf16 (512x544, zero-padded cols) ----------
__global__ void k_wconv(const float* __restrict__ W, unsigned short* __restrict__ Wb) {
  int idx = blockIdx.x * 256 + threadIdx.x;
  if (idx >= HID * KPAD) return;
  int o = idx / KPAD;
  int k = idx - o * KPAD;
  float v = (k < KIN) ? W[o * KIN + k] : 0.f;
  Wb[idx] = f2bf(v);
}

// ---------- MFMA correlation + fused x->featB transpose ----------
// Round-8 change vs round 7 (occupancy): tile narrowed to 32 px cols ->
// LDS [8 sr][36 sc][64 ch] = 36,864 B -> 4 blocks/CU (was 69,632 B -> 2).
// grid 4096 = 16 img x 16 rowgroups x 2 colgroups x 8 cs (XCD-swizzled).
// Block = 4 px rows x 32 cols; wave w = row r0+w (32 px, 2 groups of 16).
// Swizzle: slot = kg ^ (sc&7) (round-7 verified: read pattern 2-way free).
__device__ __forceinline__ int xelem(int sr, int sc, int kg) {
  return (sr * 36 + sc) * 64 + ((kg ^ (sc & 7)) * 8);
}

__global__ __launch_bounds__(256) void k_corr(const float* __restrict__ x,
                                              unsigned short* __restrict__ featB,
                                              unsigned short* __restrict__ part) {
  __shared__ unsigned short xt[8 * 36 * 64];  // 36,864 B
  int g = blockIdx.x;
  int bid = (g & 7) * 512 + (g >> 3);   // bijective XCD swizzle (grid = 8*512)
  int cs = bid & 7;
  int cg = (bid >> 3) & 1;
  int rg = (bid >> 4) & 15;
  int b  = bid >> 8;
  int t = threadIdx.x;
  int lane = t & 63;
  int w = t >> 6;
  int r0 = rg * 4, c0 = cg * 32;

  const float* xb = x + ((size_t)b * C_IN + cs * 64) * HW;

  // ---- stage: 2304 = 9*256 (sr,sc,kg) items; halo zero-padded uniformly
#pragma unroll
  for (int i = 0; i < 9; ++i) {
    int li = t + i * 256;
    int sc = li % 36;
    int t2 = li / 36;                   // 0..63
    int kg = t2 >> 3, sr = t2 & 7;
    int ir = r0 - 2 + sr, ic = c0 - 2 + sc;
    unsigned short pk[8];
    if ((unsigned)ir < 64u && (unsigned)ic < 64u) {
      const float* src = xb + ir * 64 + ic;
#pragma unroll
      for (int j = 0; j < 8; ++j) pk[j] = f2bf(src[(kg * 8 + j) * HW]);
    } else {
#pragma unroll
      for (int j = 0; j < 8; ++j) pk[j] = 0;
    }
    *(bf16x8*)&xt[xelem(sr, sc, kg)] = *(bf16x8*)pk;
  }
  __syncthreads();

  // ---- fused featB transpose: 1024 = 4*256 (px,kg) items; 128B/px contiguous
#pragma unroll
  for (int i = 0; i < 4; ++i) {
    int flat = t + i * 256;
    int px = flat >> 3, kg = flat & 7;
    int pr = px >> 5, pc = px & 31;
    int n = b * 4096 + (r0 + pr) * 64 + c0 + pc;
    *(bf16x8*)(featB + (size_t)n * KPAD + cs * 64 + kg * 8) =
        *(const bf16x8*)&xt[xelem(pr + 2, pc + 2, kg)];
  }

  // ---- MFMA: wave computes 25 (di,dj) diag-tiles for its 32-px row
  int i15 = lane & 15;
  int tq = lane >> 4;
  int q = i15 - tq * 4;                 // diag reg index; valid in [0,4)
  bool valid = (q >= 0) && (q < 4);

  bf16x8 afr[2][2];                     // A-frags: centers, reused for all 25
#pragma unroll
  for (int gg = 0; gg < 2; ++gg)
#pragma unroll
    for (int ks = 0; ks < 2; ++ks)
      afr[gg][ks] = *(const bf16x8*)&xt[xelem(w + 2, gg * 16 + 2 + i15, ks * 4 + tq)];

  int nb = b * 4096 + (r0 + w) * 64 + c0;
#pragma unroll 1
  for (int di = 0; di < 5; ++di) {
    int sr = w + di;
    unsigned short* pbase = part + ((size_t)(cs * 25 + di * 5)) * NPIX + nb;
#pragma unroll
    for (int dj = 0; dj < 5; ++dj) {
      f32x4 acc[2];
#pragma unroll
      for (int gg = 0; gg < 2; ++gg) acc[gg] = (f32x4){0.f, 0.f, 0.f, 0.f};
#pragma unroll
      for (int gg = 0; gg < 2; ++gg)
#pragma unroll
        for (int ks = 0; ks < 2; ++ks) {
          bf16x8 bfr = *(const bf16x8*)&xt[xelem(sr, gg * 16 + dj + i15, ks * 4 + tq)];
          acc[gg] = __builtin_amdgcn_mfma_f32_16x16x32_bf16(afr[gg][ks], bfr, acc[gg], 0, 0, 0);
        }
      unsigned short* pp = pbase + (size_t)dj * NPIX;
#pragma unroll
      for (int gg = 0; gg < 2; ++gg) {
        float val = (q == 0) ? acc[gg][0]
                  : (q == 1) ? acc[gg][1]
                  : (q == 2) ? acc[gg][2] : acc[gg][3];
        if (valid) pp[gg * 16 + i15] = f2bf(val);
      }
    }
  }
}

// ---------- reduce 8 partials, L2-normalize, emit featB[n][512..543] ----------
__global__ void k_norm(const unsigned short* __restrict__ part,
                       unsigned short* __restrict__ featB) {
  int n = blockIdx.x * 256 + threadIdx.x;
  float g[25];
  float ss = 0.f;
#pragma unroll
  for (int k = 0; k < 25; ++k) {
    float s = 0.f;
#pragma unroll
    for (int cs = 0; cs < 8; ++cs)
      s += bf2f(part[((size_t)cs * 25 + k) * NPIX + n]);
    g[k] = s;
    ss += s * s;
  }
  float inv = 1.0f / sqrtf(ss + 1e-6f);
  unsigned short buf[32];
#pragma unroll
  for (int k = 0; k < 25; ++k) buf[k] = f2bf(g[k] * inv);
#pragma unroll
  for (int k = 25; k < 32; ++k) buf[k] = 0;
#pragma unroll
  for (int j = 0; j < 4; ++j)
    *(bf16x8*)(featB + (size_t)n * KPAD + 512 + j * 8) = *(bf16x8*)&buf[j * 8];
}

// ---------- GEMM: out(512 x 65536) = Wb(512 x 544) * featB(65536 x 544)^T ----------
typedef __attribute__((address_space(3))) unsigned int as3_uint;
typedef const __attribute__((address_space(1))) unsigned int as1_uint;

__device__ __forceinline__ void glds16(const void* g, void* l) {
  __builtin_amdgcn_global_load_lds((as1_uint*)g, (as3_uint*)l, 16, 0, 0);
}

__global__ __launch_bounds__(256) void k_gemm(const unsigned short* __restrict__ Wb,
                                              const unsigned short* __restrict__ featB,
                                              const float* __restrict__ bias,
                                              float* __restrict__ out) {
  __shared__ __attribute__((aligned(16))) unsigned short As[2][4096]; // [128 m][32 k], swz
  __shared__ __attribute__((aligned(16))) unsigned short Bs[2][4096]; // [128 n][32 k], swz
  int g = blockIdx.x;
  int bid = (g & 7) * 256 + (g >> 3);
  int mt = bid & 3;
  int nt = bid >> 2;
  int m0 = mt * 128;
  int n0 = nt * 128;
  int tid = threadIdx.x;
  int wave = tid >> 6;
  int lane = tid & 63;
  int wm = wave >> 1;
  int wn = wave & 1;
  int kg = lane >> 4;

  uint32_t aOff[4], bOff[4];
#pragma unroll
  for (int r = 0; r < 4; ++r) {
    int rr = wm * 64 + r * 16 + (lane & 15);
    aOff[r] = rr * 64 + ((kg ^ ((rr >> 1) & 3)) << 4);
  }
#pragma unroll
  for (int cb = 0; cb < 4; ++cb) {
    int rr = wn * 64 + cb * 16 + (lane & 15);
    bOff[cb] = rr * 64 + ((kg ^ ((rr >> 1) & 3)) << 4);
  }

  f32x4 acc[4][4];
#pragma unroll
  for (int r = 0; r < 4; ++r)
#pragma unroll
    for (int cb = 0; cb < 4; ++cb)
      acc[r][cb] = (f32x4){0.f, 0.f, 0.f, 0.f};

  auto STAGE = [&](int buf, int k0) {
#pragma unroll
    for (int qq = 0; qq < 2; ++qq) {
      int ci = wave * 2 + qq;
      int i = ci * 64 + lane;
      int rr = i >> 2;
      int slot = i & 3;
      int k8 = slot ^ ((rr >> 1) & 3);
      glds16(Wb + (size_t)(m0 + rr) * KPAD + k0 + k8 * 8, (char*)&As[buf][0] + ci * 1024);
      glds16(featB + (size_t)(n0 + rr) * KPAD + k0 + k8 * 8, (char*)&Bs[buf][0] + ci * 1024);
    }
  };

  STAGE(0, 0);
  __syncthreads();
  int cur = 0;
#pragma unroll 1
  for (int t = 0; t < 17; ++t) {
    if (t < 16) STAGE(cur ^ 1, (t + 1) * 32);
    const char* Ab = (const char*)&As[cur][0];
    const char* Bb = (const char*)&Bs[cur][0];
    bf16x8 af[4], bf[4];
#pragma unroll
    for (int r = 0; r < 4; ++r)
      af[r] = *(const bf16x8*)(Ab + aOff[r]);
#pragma unroll
    for (int cb = 0; cb < 4; ++cb)
      bf[cb] = *(const bf16x8*)(Bb + bOff[cb]);
#pragma unroll
    for (int cb = 0; cb < 4; ++cb)
#pragma unroll
      for (int r = 0; r < 4; ++r)
        acc[r][cb] = __builtin_amdgcn_mfma_f32_16x16x32_bf16(af[r], bf[cb], acc[r][cb], 0, 0, 0);
    __syncthreads();
    cur ^= 1;
  }

  int bb = n0 >> 12;
  int hwb = n0 & 4095;
  float* outb = out + (size_t)bb * (HID * HW) + hwb;
#pragma unroll
  for (int r = 0; r < 4; ++r) {
    int row0 = m0 + wm * 64 + r * 16 + (lane >> 4) * 4;
    float bv[4];
#pragma unroll
    for (int j = 0; j < 4; ++j) bv[j] = bias[row0 + j];
#pragma unroll
    for (int cb = 0; cb < 4; ++cb) {
      int col = wn * 64 + cb * 16 + (lane & 15);
#pragma unroll
      for (int j = 0; j < 4; ++j) {
        float v2 = acc[r][cb][j] + bv[j];
        v2 = fmaxf(v2, 0.f);
        outb[(size_t)(row0 + j) * HW + col] = v2;
      }
    }
  }
}

extern "C" void kernel_launch(void* const* d_in, const int* in_sizes, int n_in,
                              void* d_out, int out_size, void* d_ws, size_t ws_size,
                              hipStream_t stream) {
  const float* x = (const float*)d_in[0];
  const float* W = (const float*)d_in[1];
  const float* bias = (const float*)d_in[2];
  float* out = (float*)d_out;
  char* ws = (char*)d_ws;
  // ws: featB 65536x544 bf16 = 71,303,168; Wb 512x544 bf16 = 557,056;
  //     part 8x25x65536 bf16 = 26,214,400  (total ~98.07 MB)
  unsigned short* featB = (unsigned short*)ws;
  unsigned short* Wb = (unsigned short*)(ws + 71303168);
  unsigned short* part = (unsigned short*)(ws + 71860224);

  k_wconv<<<1088, 256, 0, stream>>>(W, Wb);
  k_corr<<<4096, 256, 0, stream>>>(x, featB, part);
  k_norm<<<256, 256, 0, stream>>>(part, featB);
  k_gemm<<<2048, 256, 0, stream>>>(Wb, featB, bias, out);
}

// Round 9
// 168.663 us; speedup vs baseline: 8.7159x; 1.0510x over previous
//
#include <hip/hip_runtime.h>
#include <stdint.h>

#define C_IN 512
#define HW 4096
#define NPIX 65536
#define KPAD 544
#define KIN 537
#define HID 512

typedef __attribute__((ext_vector_type(8))) short bf16x8;
typedef __attribute__((ext_vector_type(4))) float f32x4;

__device__ __forceinline__ unsigned short f2bf(float f) {
  union { float f; uint32_t u; } v; v.f = f;
  uint32_t u = v.u;
  return (unsigned short)((u + 0x7fffu + ((u >> 16) & 1u)) >> 16);
}
__device__ __forceinline__ float bf2f(unsigned short h) {
  union { uint32_t u; float f; } v; v.u = ((uint32_t)h) << 16;
  return v.f;
}

// ---------- W: fp32 (512x537) -> bf16 (512x544, zero-padded cols) ----------
__global__ void k_wconv(const float* __restrict__ W, unsigned short* __restrict__ Wb) {
  int idx = blockIdx.x * 256 + threadIdx.x;
  if (idx >= HID * KPAD) return;
  int o = idx / KPAD;
  int k = idx - o * KPAD;
  float v = (k < KIN) ? W[o * KIN + k] : 0.f;
  Wb[idx] = f2bf(v);
}

// ---------- MFMA correlation + fused x->featB transpose ----------
// Round-9 change vs round 8 (occupancy, isolated): tile narrowed 32->16 px cols.
// LDS [8 sr][20 sc][64 ch] = 20,480 B -> 8 blocks/CU = 32 waves/CU (HW cap).
// grid 8192 = 16 img x 16 rowgroups x 4 colgroups x 8 cs (XCD-swizzled).
// Block = 4 px rows x 16 cols; wave w = row r0+w (one 16-px MFMA group).
// Swizzle: slot = kg ^ (sc&7) (round-7 verified: 31x conflict reduction).
__device__ __forceinline__ int xelem(int sr, int sc, int kg) {
  return (sr * 20 + sc) * 64 + ((kg ^ (sc & 7)) * 8);
}

__global__ __launch_bounds__(256) void k_corr(const float* __restrict__ x,
                                              unsigned short* __restrict__ featB,
                                              unsigned short* __restrict__ part) {
  __shared__ unsigned short xt[8 * 20 * 64];  // 20,480 B
  int g = blockIdx.x;
  int bid = (g & 7) * 1024 + (g >> 3);  // bijective XCD swizzle (grid = 8*1024)
  int cs = bid & 7;
  int cg = (bid >> 3) & 3;
  int rg = (bid >> 5) & 15;
  int b  = bid >> 9;
  int t = threadIdx.x;
  int lane = t & 63;
  int w = t >> 6;
  int r0 = rg * 4, c0 = cg * 16;

  const float* xb = x + ((size_t)b * C_IN + cs * 64) * HW;

  // ---- stage: 1280 = 5*256 (sr,sc,kg) items; halo zero-padded uniformly
#pragma unroll
  for (int i = 0; i < 5; ++i) {
    int li = t + i * 256;
    int sc = li % 20;
    int t2 = li / 20;                   // 0..63
    int kg = t2 >> 3, sr = t2 & 7;
    int ir = r0 - 2 + sr, ic = c0 - 2 + sc;
    unsigned short pk[8];
    if ((unsigned)ir < 64u && (unsigned)ic < 64u) {
      const float* src = xb + ir * 64 + ic;
#pragma unroll
      for (int j = 0; j < 8; ++j) pk[j] = f2bf(src[(kg * 8 + j) * HW]);
    } else {
#pragma unroll
      for (int j = 0; j < 8; ++j) pk[j] = 0;
    }
    *(bf16x8*)&xt[xelem(sr, sc, kg)] = *(bf16x8*)pk;
  }
  __syncthreads();

  // ---- fused featB transpose: 512 = 2*256 (px,kg) items; 128B/px contiguous
#pragma unroll
  for (int i = 0; i < 2; ++i) {
    int flat = t + i * 256;
    int px = flat >> 3, kg = flat & 7;
    int pr = px >> 4, pc = px & 15;
    int n = b * 4096 + (r0 + pr) * 64 + c0 + pc;
    *(bf16x8*)(featB + (size_t)n * KPAD + cs * 64 + kg * 8) =
        *(const bf16x8*)&xt[xelem(pr + 2, pc + 2, kg)];
  }

  // ---- MFMA: wave computes 25 (di,dj) diag-tiles for its 16-px row
  int i15 = lane & 15;
  int tq = lane >> 4;
  int q = i15 - tq * 4;                 // diag reg index; valid in [0,4)
  bool valid = (q >= 0) && (q < 4);

  bf16x8 afr[2];                        // A-frags: centers, reused for all 25
#pragma unroll
  for (int ks = 0; ks < 2; ++ks)
    afr[ks] = *(const bf16x8*)&xt[xelem(w + 2, 2 + i15, ks * 4 + tq)];

  int nb = b * 4096 + (r0 + w) * 64 + c0;
#pragma unroll 1
  for (int di = 0; di < 5; ++di) {
    int sr = w + di;
    unsigned short* pbase = part + ((size_t)(cs * 25 + di * 5)) * NPIX + nb;
#pragma unroll
    for (int dj = 0; dj < 5; ++dj) {
      f32x4 acc = (f32x4){0.f, 0.f, 0.f, 0.f};
#pragma unroll
      for (int ks = 0; ks < 2; ++ks) {
        bf16x8 bfr = *(const bf16x8*)&xt[xelem(sr, dj + i15, ks * 4 + tq)];
        acc = __builtin_amdgcn_mfma_f32_16x16x32_bf16(afr[ks], bfr, acc, 0, 0, 0);
      }
      float val = (q == 0) ? acc[0]
                : (q == 1) ? acc[1]
                : (q == 2) ? acc[2] : acc[3];
      if (valid) pbase[(size_t)dj * NPIX + i15] = f2bf(val);
    }
  }
}

// ---------- reduce 8 partials, L2-normalize, emit featB[n][512..543] ----------
__global__ void k_norm(const unsigned short* __restrict__ part,
                       unsigned short* __restrict__ featB) {
  int n = blockIdx.x * 256 + threadIdx.x;
  float g[25];
  float ss = 0.f;
#pragma unroll
  for (int k = 0; k < 25; ++k) {
    float s = 0.f;
#pragma unroll
    for (int cs = 0; cs < 8; ++cs)
      s += bf2f(part[((size_t)cs * 25 + k) * NPIX + n]);
    g[k] = s;
    ss += s * s;
  }
  float inv = 1.0f / sqrtf(ss + 1e-6f);
  unsigned short buf[32];
#pragma unroll
  for (int k = 0; k < 25; ++k) buf[k] = f2bf(g[k] * inv);
#pragma unroll
  for (int k = 25; k < 32; ++k) buf[k] = 0;
#pragma unroll
  for (int j = 0; j < 4; ++j)
    *(bf16x8*)(featB + (size_t)n * KPAD + 512 + j * 8) = *(bf16x8*)&buf[j * 8];
}

// ---------- GEMM: out(512 x 65536) = Wb(512 x 544) * featB(65536 x 544)^T ----------
typedef __attribute__((address_space(3))) unsigned int as3_uint;
typedef const __attribute__((address_space(1))) unsigned int as1_uint;

__device__ __forceinline__ void glds16(const void* g, void* l) {
  __builtin_amdgcn_global_load_lds((as1_uint*)g, (as3_uint*)l, 16, 0, 0);
}

__global__ __launch_bounds__(256) void k_gemm(const unsigned short* __restrict__ Wb,
                                              const unsigned short* __restrict__ featB,
                                              const float* __restrict__ bias,
                                              float* __restrict__ out) {
  __shared__ __attribute__((aligned(16))) unsigned short As[2][4096]; // [128 m][32 k], swz
  __shared__ __attribute__((aligned(16))) unsigned short Bs[2][4096]; // [128 n][32 k], swz
  int g = blockIdx.x;
  int bid = (g & 7) * 256 + (g >> 3);
  int mt = bid & 3;
  int nt = bid >> 2;
  int m0 = mt * 128;
  int n0 = nt * 128;
  int tid = threadIdx.x;
  int wave = tid >> 6;
  int lane = tid & 63;
  int wm = wave >> 1;
  int wn = wave & 1;
  int kg = lane >> 4;

  uint32_t aOff[4], bOff[4];
#pragma unroll
  for (int r = 0; r < 4; ++r) {
    int rr = wm * 64 + r * 16 + (lane & 15);
    aOff[r] = rr * 64 + ((kg ^ ((rr >> 1) & 3)) << 4);
  }
#pragma unroll
  for (int cb = 0; cb < 4; ++cb) {
    int rr = wn * 64 + cb * 16 + (lane & 15);
    bOff[cb] = rr * 64 + ((kg ^ ((rr >> 1) & 3)) << 4);
  }

  f32x4 acc[4][4];
#pragma unroll
  for (int r = 0; r < 4; ++r)
#pragma unroll
    for (int cb = 0; cb < 4; ++cb)
      acc[r][cb] = (f32x4){0.f, 0.f, 0.f, 0.f};

  auto STAGE = [&](int buf, int k0) {
#pragma unroll
    for (int qq = 0; qq < 2; ++qq) {
      int ci = wave * 2 + qq;
      int i = ci * 64 + lane;
      int rr = i >> 2;
      int slot = i & 3;
      int k8 = slot ^ ((rr >> 1) & 3);
      glds16(Wb + (size_t)(m0 + rr) * KPAD + k0 + k8 * 8, (char*)&As[buf][0] + ci * 1024);
      glds16(featB + (size_t)(n0 + rr) * KPAD + k0 + k8 * 8, (char*)&Bs[buf][0] + ci * 1024);
    }
  };

  STAGE(0, 0);
  __syncthreads();
  int cur = 0;
#pragma unroll 1
  for (int t = 0; t < 17; ++t) {
    if (t < 16) STAGE(cur ^ 1, (t + 1) * 32);
    const char* Ab = (const char*)&As[cur][0];
    const char* Bb = (const char*)&Bs[cur][0];
    bf16x8 af[4], bf[4];
#pragma unroll
    for (int r = 0; r < 4; ++r)
      af[r] = *(const bf16x8*)(Ab + aOff[r]);
#pragma unroll
    for (int cb = 0; cb < 4; ++cb)
      bf[cb] = *(const bf16x8*)(Bb + bOff[cb]);
#pragma unroll
    for (int cb = 0; cb < 4; ++cb)
#pragma unroll
      for (int r = 0; r < 4; ++r)
        acc[r][cb] = __builtin_amdgcn_mfma_f32_16x16x32_bf16(af[r], bf[cb], acc[r][cb], 0, 0, 0);
    __syncthreads();
    cur ^= 1;
  }

  int bb = n0 >> 12;
  int hwb = n0 & 4095;
  float* outb = out + (size_t)bb * (HID * HW) + hwb;
#pragma unroll
  for (int r = 0; r < 4; ++r) {
    int row0 = m0 + wm * 64 + r * 16 + (lane >> 4) * 4;
    float bv[4];
#pragma unroll
    for (int j = 0; j < 4; ++j) bv[j] = bias[row0 + j];
#pragma unroll
    for (int cb = 0; cb < 4; ++cb) {
      int col = wn * 64 + cb * 16 + (lane & 15);
#pragma unroll
      for (int j = 0; j < 4; ++j) {
        float v2 = acc[r][cb][j] + bv[j];
        v2 = fmaxf(v2, 0.f);
        outb[(size_t)(row0 + j) * HW + col] = v2;
      }
    }
  }
}

extern "C" void kernel_launch(void* const* d_in, const int* in_sizes, int n_in,
                              void* d_out, int out_size, void* d_ws, size_t ws_size,
                              hipStream_t stream) {
  const float* x = (const float*)d_in[0];
  const float* W = (const float*)d_in[1];
  const float* bias = (const float*)d_in[2];
  float* out = (float*)d_out;
  char* ws = (char*)d_ws;
  // ws: featB 65536x544 bf16 = 71,303,168; Wb 512x544 bf16 = 557,056;
  //     part 8x25x65536 bf16 = 26,214,400  (total ~98.07 MB)
  unsigned short* featB = (unsigned short*)ws;
  unsigned short* Wb = (unsigned short*)(ws + 71303168);
  unsigned short* part = (unsigned short*)(ws + 71860224);

  k_wconv<<<1088, 256, 0, stream>>>(W, Wb);
  k_corr<<<8192, 256, 0, stream>>>(x, featB, part);
  k_norm<<<256, 256, 0, stream>>>(part, featB);
  k_gemm<<<2048, 256, 0, stream>>>(Wb, featB, bias, out);
}

// Round 10
// 151.202 us; speedup vs baseline: 9.7224x; 1.1155x over previous
//
#include <hip/hip_runtime.h>
#include <stdint.h>

#define C_IN 512
#define HW 4096
#define NPIX 65536
#define KPAD 544
#define KIN 537
#define HID 512

typedef __attribute__((ext_vector_type(8))) short bf16x8;
typedef __attribute__((ext_vector_type(4))) float f32x4;

__device__ __forceinline__ unsigned short f2bf(float f) {
  union { float f; uint32_t u; } v; v.f = f;
  uint32_t u = v.u;
  return (unsigned short)((u + 0x7fffu + ((u >> 16) & 1u)) >> 16);
}
__device__ __forceinline__ float bf2f(unsigned short h) {
  union { uint32_t u; float f; } v; v.u = ((uint32_t)h) << 16;
  return v.f;
}

// ---------- W: fp32 (512x537) -> bf16 (512x544, zero-padded cols) ----------
__global__ void k_wconv(const float* __restrict__ W, unsigned short* __restrict__ Wb) {
  int idx = blockIdx.x * 256 + threadIdx.x;
  if (idx >= HID * KPAD) return;
  int o = idx / KPAD;
  int k = idx - o * KPAD;
  float v = (k < KIN) ? W[o * KIN + k] : 0.f;
  Wb[idx] = f2bf(v);
}

// ---------- x fp32 [c][n] -> featB bf16 [n][c] (convert once, coalesced) ----------
// grid 8192 = 16 img x 8 ch-groups x 64 px-tiles; block 256 = 4 waves.
// Tile 64 ch x 64 px via LDS [64 px][70 ch] (pad 70: lane*35%32 -> 2-way, free).
__global__ __launch_bounds__(256, 8) void k_xpose(const float* __restrict__ x,
                                                  unsigned short* __restrict__ featB) {
  __shared__ unsigned short sm[64][70];
  int g = blockIdx.x;
  int b = g >> 9, cg = (g >> 6) & 7, pt = g & 63;
  int c0 = cg * 64, p0 = pt * 64;
  int t = threadIdx.x, lane = t & 63, w = t >> 6;
  const float* xb = x + ((size_t)b * C_IN + c0) * HW + p0;
#pragma unroll
  for (int i = 0; i < 8; ++i) {
    int ch = w * 16 + i * 2;
    float a = xb[(size_t)ch * HW + lane];
    float bq = xb[(size_t)(ch + 1) * HW + lane];
    uint32_t pk = (uint32_t)f2bf(a) | ((uint32_t)f2bf(bq) << 16);
    *(uint32_t*)&sm[lane][ch] = pk;   // ch even, 4B-aligned
  }
  __syncthreads();
#pragma unroll
  for (int i = 0; i < 2; ++i) {
    int px = (t >> 3) + i * 32, kg = t & 7;
    int n = b * 4096 + p0 + px;
    *(bf16x8*)(featB + (size_t)n * KPAD + c0 + kg * 8) = *(const bf16x8*)&sm[px][kg * 8];
  }
}

// ---------- MFMA correlation (stages bf16 from featB; no conversion) ----------
// LDS [8 sr][20 sc][64 ch] = 20,480 B -> 8 blocks/CU = 32 waves/CU.
// grid 8192 = 16 img x 16 rowgroups x 4 colgroups x 8 cs (XCD-swizzled).
// Block = 4 px rows x 16 cols; wave w = row r0+w (one 16-px MFMA group).
// Swizzle: slot = kg ^ (sc&7) (round-7 verified: 31x conflict reduction).
__device__ __forceinline__ int xelem(int sr, int sc, int kg) {
  return (sr * 20 + sc) * 64 + ((kg ^ (sc & 7)) * 8);
}

__global__ __launch_bounds__(256, 8) void k_corr(const unsigned short* __restrict__ featB,
                                                 unsigned short* __restrict__ part) {
  __shared__ unsigned short xt[8 * 20 * 64];  // 20,480 B
  int g = blockIdx.x;
  int bid = (g & 7) * 1024 + (g >> 3);  // bijective XCD swizzle (grid = 8*1024)
  int cs = bid & 7;
  int cg = (bid >> 3) & 3;
  int rg = (bid >> 5) & 15;
  int b  = bid >> 9;
  int t = threadIdx.x;
  int lane = t & 63;
  int w = t >> 6;
  int r0 = rg * 4, c0 = cg * 16;

  // ---- stage: 1280 = 5*256 (px,kg) items from featB; 8 lanes = one px's 128B
  bf16x8 v[5];
  int la[5];
#pragma unroll
  for (int i = 0; i < 5; ++i) {
    int flat = t + i * 256;
    int kg = flat & 7, pxi = flat >> 3;
    int sc = pxi % 20, sr = pxi / 20;
    int ir = r0 - 2 + sr, ic = c0 - 2 + sc;
    la[i] = xelem(sr, sc, kg);
    if ((unsigned)ir < 64u && (unsigned)ic < 64u) {
      int n = b * 4096 + ir * 64 + ic;
      v[i] = *(const bf16x8*)(featB + (size_t)n * KPAD + cs * 64 + kg * 8);
    } else {
      v[i] = (bf16x8){0, 0, 0, 0, 0, 0, 0, 0};
    }
  }
#pragma unroll
  for (int i = 0; i < 5; ++i)
    *(bf16x8*)&xt[la[i]] = v[i];
  __syncthreads();

  // ---- MFMA: wave computes 25 (di,dj) diag-tiles for its 16-px row
  int i15 = lane & 15;
  int tq = lane >> 4;
  int q = i15 - tq * 4;                 // diag reg index; valid in [0,4)
  bool valid = (q >= 0) && (q < 4);

  bf16x8 afr[2];                        // A-frags: centers, reused for all 25
#pragma unroll
  for (int ks = 0; ks < 2; ++ks)
    afr[ks] = *(const bf16x8*)&xt[xelem(w + 2, 2 + i15, ks * 4 + tq)];

  int nb = b * 4096 + (r0 + w) * 64 + c0;
#pragma unroll 1
  for (int di = 0; di < 5; ++di) {
    int sr = w + di;
    unsigned short* pbase = part + ((size_t)(cs * 25 + di * 5)) * NPIX + nb;
#pragma unroll
    for (int dj = 0; dj < 5; ++dj) {
      f32x4 acc = (f32x4){0.f, 0.f, 0.f, 0.f};
#pragma unroll
      for (int ks = 0; ks < 2; ++ks) {
        bf16x8 bfr = *(const bf16x8*)&xt[xelem(sr, dj + i15, ks * 4 + tq)];
        acc = __builtin_amdgcn_mfma_f32_16x16x32_bf16(afr[ks], bfr, acc, 0, 0, 0);
      }
      float val = (q == 0) ? acc[0]
                : (q == 1) ? acc[1]
                : (q == 2) ? acc[2] : acc[3];
      if (valid) pbase[(size_t)dj * NPIX + i15] = f2bf(val);
    }
  }
}

// ---------- reduce 8 partials, L2-normalize, emit featB[n][512..543] ----------
__global__ void k_norm(const unsigned short* __restrict__ part,
                       unsigned short* __restrict__ featB) {
  int n = blockIdx.x * 256 + threadIdx.x;
  float g[25];
  float ss = 0.f;
#pragma unroll
  for (int k = 0; k < 25; ++k) {
    float s = 0.f;
#pragma unroll
    for (int cs = 0; cs < 8; ++cs)
      s += bf2f(part[((size_t)cs * 25 + k) * NPIX + n]);
    g[k] = s;
    ss += s * s;
  }
  float inv = 1.0f / sqrtf(ss + 1e-6f);
  unsigned short buf[32];
#pragma unroll
  for (int k = 0; k < 25; ++k) buf[k] = f2bf(g[k] * inv);
#pragma unroll
  for (int k = 25; k < 32; ++k) buf[k] = 0;
#pragma unroll
  for (int j = 0; j < 4; ++j)
    *(bf16x8*)(featB + (size_t)n * KPAD + 512 + j * 8) = *(bf16x8*)&buf[j * 8];
}

// ---------- GEMM: out(512 x 65536) = Wb(512 x 544) * featB(65536 x 544)^T ----------
typedef __attribute__((address_space(3))) unsigned int as3_uint;
typedef const __attribute__((address_space(1))) unsigned int as1_uint;

__device__ __forceinline__ void glds16(const void* g, void* l) {
  __builtin_amdgcn_global_load_lds((as1_uint*)g, (as3_uint*)l, 16, 0, 0);
}

__global__ __launch_bounds__(256) void k_gemm(const unsigned short* __restrict__ Wb,
                                              const unsigned short* __restrict__ featB,
                                              const float* __restrict__ bias,
                                              float* __restrict__ out) {
  __shared__ __attribute__((aligned(16))) unsigned short As[2][4096]; // [128 m][32 k], swz
  __shared__ __attribute__((aligned(16))) unsigned short Bs[2][4096]; // [128 n][32 k], swz
  int g = blockIdx.x;
  int bid = (g & 7) * 256 + (g >> 3);
  int mt = bid & 3;
  int nt = bid >> 2;
  int m0 = mt * 128;
  int n0 = nt * 128;
  int tid = threadIdx.x;
  int wave = tid >> 6;
  int lane = tid & 63;
  int wm = wave >> 1;
  int wn = wave & 1;
  int kg = lane >> 4;

  uint32_t aOff[4], bOff[4];
#pragma unroll
  for (int r = 0; r < 4; ++r) {
    int rr = wm * 64 + r * 16 + (lane & 15);
    aOff[r] = rr * 64 + ((kg ^ ((rr >> 1) & 3)) << 4);
  }
#pragma unroll
  for (int cb = 0; cb < 4; ++cb) {
    int rr = wn * 64 + cb * 16 + (lane & 15);
    bOff[cb] = rr * 64 + ((kg ^ ((rr >> 1) & 3)) << 4);
  }

  f32x4 acc[4][4];
#pragma unroll
  for (int r = 0; r < 4; ++r)
#pragma unroll
    for (int cb = 0; cb < 4; ++cb)
      acc[r][cb] = (f32x4){0.f, 0.f, 0.f, 0.f};

  auto STAGE = [&](int buf, int k0) {
#pragma unroll
    for (int qq = 0; qq < 2; ++qq) {
      int ci = wave * 2 + qq;
      int i = ci * 64 + lane;
      int rr = i >> 2;
      int slot = i & 3;
      int k8 = slot ^ ((rr >> 1) & 3);
      glds16(Wb + (size_t)(m0 + rr) * KPAD + k0 + k8 * 8, (char*)&As[buf][0] + ci * 1024);
      glds16(featB + (size_t)(n0 + rr) * KPAD + k0 + k8 * 8, (char*)&Bs[buf][0] + ci * 1024);
    }
  };

  STAGE(0, 0);
  __syncthreads();
  int cur = 0;
#pragma unroll 1
  for (int t = 0; t < 17; ++t) {
    if (t < 16) STAGE(cur ^ 1, (t + 1) * 32);
    const char* Ab = (const char*)&As[cur][0];
    const char* Bb = (const char*)&Bs[cur][0];
    bf16x8 af[4], bf[4];
#pragma unroll
    for (int r = 0; r < 4; ++r)
      af[r] = *(const bf16x8*)(Ab + aOff[r]);
#pragma unroll
    for (int cb = 0; cb < 4; ++cb)
      bf[cb] = *(const bf16x8*)(Bb + bOff[cb]);
#pragma unroll
    for (int cb = 0; cb < 4; ++cb)
#pragma unroll
      for (int r = 0; r < 4; ++r)
        acc[r][cb] = __builtin_amdgcn_mfma_f32_16x16x32_bf16(af[r], bf[cb], acc[r][cb], 0, 0, 0);
    __syncthreads();
    cur ^= 1;
  }

  int bb = n0 >> 12;
  int hwb = n0 & 4095;
  float* outb = out + (size_t)bb * (HID * HW) + hwb;
#pragma unroll
  for (int r = 0; r < 4; ++r) {
    int row0 = m0 + wm * 64 + r * 16 + (lane >> 4) * 4;
    float bv[4];
#pragma unroll
    for (int j = 0; j < 4; ++j) bv[j] = bias[row0 + j];
#pragma unroll
    for (int cb = 0; cb < 4; ++cb) {
      int col = wn * 64 + cb * 16 + (lane & 15);
#pragma unroll
      for (int j = 0; j < 4; ++j) {
        float v2 = acc[r][cb][j] + bv[j];
        v2 = fmaxf(v2, 0.f);
        outb[(size_t)(row0 + j) * HW + col] = v2;
      }
    }
  }
}

extern "C" void kernel_launch(void* const* d_in, const int* in_sizes, int n_in,
                              void* d_out, int out_size, void* d_ws, size_t ws_size,
                              hipStream_t stream) {
  const float* x = (const float*)d_in[0];
  const float* W = (const float*)d_in[1];
  const float* bias = (const float*)d_in[2];
  float* out = (float*)d_out;
  char* ws = (char*)d_ws;
  // ws: featB 65536x544 bf16 = 71,303,168; Wb 512x544 bf16 = 557,056;
  //     part 8x25x65536 bf16 = 26,214,400  (total ~98.07 MB)
  unsigned short* featB = (unsigned short*)ws;
  unsigned short* Wb = (unsigned short*)(ws + 71303168);
  unsigned short* part = (unsigned short*)(ws + 71860224);

  k_wconv<<<1088, 256, 0, stream>>>(W, Wb);
  k_xpose<<<8192, 256, 0, stream>>>(x, featB);
  k_corr<<<8192, 256, 0, stream>>>(featB, part);
  k_norm<<<256, 256, 0, stream>>>(part, featB);
  k_gemm<<<2048, 256, 0, stream>>>(Wb, featB, bias, out);
}